// Round 6
// baseline (319.976 us; speedup 1.0000x reference)
//
#include <hip/hip_runtime.h>
#include <hip/hip_bf16.h>

#define NN 50000
#define NE 800000
#define FD 256
#define NN_PAD 50048       // NN rounded up to multiple of 64
#define NPB 16             // nodes per block

typedef __attribute__((ext_vector_type(8))) short bf16x8;
typedef __attribute__((ext_vector_type(4))) float f32x4;
typedef unsigned long long ull;

__device__ __forceinline__ short f2bf(float f) {
    union { float f; unsigned u; } v; v.f = f;
    unsigned r = v.u + 0x7fffu + ((v.u >> 16) & 1u);
    return (short)(r >> 16);
}
__device__ __forceinline__ float bf2f(unsigned short u) {
    union { unsigned u; float f; } v; v.u = ((unsigned)u) << 16;
    return v.f;
}

// dc[row] += (1<<40) | fix24(cv)   -- one 64b atomic per edge
__global__ void count_deg_kernel(const int* __restrict__ row, const float* __restrict__ cv,
                                 ull* __restrict__ dc) {
    int e = blockIdx.x * blockDim.x + threadIdx.x;
    if (e < NE) {
        int r = row[e];
        unsigned cf = (unsigned)(cv[e] * 16777216.0f + 0.5f);
        atomicAdd(&dc[r], (1ULL << 40) | (ull)cf);
    }
}

// single block, 1024 threads: dinv = deg^-1/2; rs = exclusive scan of counts; cursor = rs
__global__ void scan_all_kernel(const ull* __restrict__ dc, float* __restrict__ dinv,
                                int* __restrict__ rs, int* __restrict__ cursor) {
    const int PER = 49;  // 1024*49 >= 50000
    __shared__ int wsum[16];
    int tid = threadIdx.x, lane = tid & 63, wv = tid >> 6;
    int base = tid * PER;
    int vals[PER];
    int local = 0;
#pragma unroll
    for (int k = 0; k < PER; ++k) {
        int i = base + k;
        int cnt = 0;
        if (i < NN) {
            ull v = dc[i];
            cnt = (int)(v >> 40);
            ull df = v & ((1ULL << 40) - 1);
            float d = (float)df * (1.0f / 16777216.0f);
            dinv[i] = (df > 0) ? rsqrtf(d) : 0.f;
        }
        vals[k] = cnt; local += cnt;
    }
    int incl = local;
#pragma unroll
    for (int off = 1; off < 64; off <<= 1) {
        int t = __shfl_up(incl, off, 64);
        if (lane >= off) incl += t;
    }
    if (lane == 63) wsum[wv] = incl;
    __syncthreads();
    if (wv == 0) {
        int s = (lane < 16) ? wsum[lane] : 0;
#pragma unroll
        for (int off = 1; off < 16; off <<= 1) {
            int t = __shfl_up(s, off, 64);
            if (lane >= off) s += t;
        }
        if (lane < 16) wsum[lane] = s;
    }
    __syncthreads();
    int woff = (wv == 0) ? 0 : wsum[wv - 1];
    int excl = woff + incl - local;
#pragma unroll
    for (int k = 0; k < PER; ++k) {
        int i = base + k;
        if (i < NN) { rs[i] = excl; cursor[i] = excl; excl += vals[k]; }
    }
    if (tid == 1023) rs[NN] = excl;   // == NE
}

// one wave per x-row: xd = x*dinv[r]; s = max|xd|/127; q8 = round(xd*127/max)+128 packed;
// tail blocks convert W -> bf16
__global__ void quant_kernel(const float* __restrict__ x, const float* __restrict__ W,
                             const float* __restrict__ dinv, unsigned* __restrict__ q8,
                             float* __restrict__ scale, short* __restrict__ Wb) {
    int wid = blockIdx.x * 4 + (threadIdx.x >> 6);
    int lane = threadIdx.x & 63;
    if (wid < NN) {
        int r = wid;
        float dr = dinv[r];
        float4 v = *(const float4*)(x + (size_t)r * FD + lane * 4);
        v.x *= dr; v.y *= dr; v.z *= dr; v.w *= dr;
        float m = fmaxf(fmaxf(fabsf(v.x), fabsf(v.y)), fmaxf(fabsf(v.z), fabsf(v.w)));
#pragma unroll
        for (int off = 1; off < 64; off <<= 1) m = fmaxf(m, __shfl_xor(m, off, 64));
        float s   = (m > 0.f) ? m * (1.0f / 127.0f) : 1.0f;
        float inv = (m > 0.f) ? 127.0f / m : 0.f;
        if (lane == 0) scale[r] = s;
        int q0 = (int)rintf(v.x * inv) + 128;
        int q1 = (int)rintf(v.y * inv) + 128;
        int q2 = (int)rintf(v.z * inv) + 128;
        int q3 = (int)rintf(v.w * inv) + 128;
        q8[r * 64 + lane] = (unsigned)q0 | ((unsigned)q1 << 8) |
                            ((unsigned)q2 << 16) | ((unsigned)q3 << 24);
    } else {
        int j = (wid - NN) * 64 + lane;
        if (j < FD * FD) Wb[j] = f2bf(W[j]);
    }
}

// counting-sort edges by destination; pack (w_bf16:16 | col:16), w = cv * scale[col]
__global__ void bucket_kernel(const int* __restrict__ row, const int* __restrict__ col,
                              const float* __restrict__ cv, const float* __restrict__ scale,
                              int* __restrict__ cursor, unsigned* __restrict__ e_cw) {
    int e = blockIdx.x * blockDim.x + threadIdx.x;
    if (e >= NE) return;
    int r = row[e], c = col[e];
    float w = cv[e] * scale[c];
    int idx = atomicAdd(&cursor[r], 1);
    unsigned wb = (unsigned)(unsigned short)f2bf(w);
    e_cw[idx] = (wb << 16) | (unsigned)c;
}

// fused gather (uint8 x, per-row scale folded into edge weight) + bf16 MFMA GEMM.
// Block = 16 nodes, 4 waves; quad (16 lanes) per node, lane = 16 feats (uint4 = 16B).
__global__ __launch_bounds__(256) void fused_kernel(
        const unsigned* __restrict__ q8, const unsigned* __restrict__ e_cw,
        const int* __restrict__ rs, const float* __restrict__ dinv,
        const short* __restrict__ Wb, const float* __restrict__ bias,
        float* __restrict__ out) {
    __shared__ short Ab[NPB][264];
    int tid = threadIdx.x, lane = tid & 63, wv = tid >> 6;
    int q = lane >> 4, i = lane & 15;
    int nbase = blockIdx.x * NPB;
    int n = nbase + wv * 4 + q;

    int e = rs[n], en = rs[n + 1];
    const unsigned* xq = q8 + i * 4;

    float acc[16];
#pragma unroll
    for (int k = 0; k < 16; ++k) acc[k] = 0.f;
    float wsum = 0.f;

#define EDGE(V, CW) do {                                                     \
        float w_ = bf2f((unsigned short)((CW) >> 16));                       \
        wsum += w_;                                                          \
        acc[0]  = fmaf(w_, (float)(unsigned char)((V).x      ), acc[0]);     \
        acc[1]  = fmaf(w_, (float)(unsigned char)((V).x >>  8), acc[1]);     \
        acc[2]  = fmaf(w_, (float)(unsigned char)((V).x >> 16), acc[2]);     \
        acc[3]  = fmaf(w_, (float)((V).x >> 24), acc[3]);                    \
        acc[4]  = fmaf(w_, (float)(unsigned char)((V).y      ), acc[4]);     \
        acc[5]  = fmaf(w_, (float)(unsigned char)((V).y >>  8), acc[5]);     \
        acc[6]  = fmaf(w_, (float)(unsigned char)((V).y >> 16), acc[6]);     \
        acc[7]  = fmaf(w_, (float)((V).y >> 24), acc[7]);                    \
        acc[8]  = fmaf(w_, (float)(unsigned char)((V).z      ), acc[8]);     \
        acc[9]  = fmaf(w_, (float)(unsigned char)((V).z >>  8), acc[9]);     \
        acc[10] = fmaf(w_, (float)(unsigned char)((V).z >> 16), acc[10]);    \
        acc[11] = fmaf(w_, (float)((V).z >> 24), acc[11]);                   \
        acc[12] = fmaf(w_, (float)(unsigned char)((V).w      ), acc[12]);    \
        acc[13] = fmaf(w_, (float)(unsigned char)((V).w >>  8), acc[13]);    \
        acc[14] = fmaf(w_, (float)(unsigned char)((V).w >> 16), acc[14]);    \
        acc[15] = fmaf(w_, (float)((V).w >> 24), acc[15]);                   \
    } while (0)

    // head-peel to 16B alignment of e_cw
    while (e < en && (e & 3)) {
        unsigned cw = e_cw[e];
        uint4 v = *(const uint4*)(xq + (size_t)(cw & 0xFFFFu) * 64);
        EDGE(v, cw);
        ++e;
    }
    // main: 4 edges per iteration, 1 metadata load + 4 x-row loads in flight
    for (; e + 4 <= en; e += 4) {
        uint4 cw4 = *(const uint4*)(e_cw + e);
        uint4 v0 = *(const uint4*)(xq + (size_t)(cw4.x & 0xFFFFu) * 64);
        uint4 v1 = *(const uint4*)(xq + (size_t)(cw4.y & 0xFFFFu) * 64);
        uint4 v2 = *(const uint4*)(xq + (size_t)(cw4.z & 0xFFFFu) * 64);
        uint4 v3 = *(const uint4*)(xq + (size_t)(cw4.w & 0xFFFFu) * 64);
        EDGE(v0, cw4.x);
        EDGE(v1, cw4.y);
        EDGE(v2, cw4.z);
        EDGE(v3, cw4.w);
    }
    for (; e < en; ++e) {
        unsigned cw = e_cw[e];
        uint4 v = *(const uint4*)(xq + (size_t)(cw & 0xFFFFu) * 64);
        EDGE(v, cw);
    }
#undef EDGE

    // remove the +128 bias, apply dinv[row], convert to bf16 in LDS
    {
        float dr = dinv[n];
        float base = 128.f * wsum;
        bf16x8 lo, hi;
#pragma unroll
        for (int k = 0; k < 8; ++k) {
            lo[k] = f2bf((acc[k] - base) * dr);
            hi[k] = f2bf((acc[k + 8] - base) * dr);
        }
        *(bf16x8*)&Ab[wv * 4 + q][i * 16] = lo;
        *(bf16x8*)&Ab[wv * 4 + q][i * 16 + 8] = hi;
    }
    __syncthreads();

    // ---- GEMM: out[nbase..+16][wv*64..+64] via 16x16x32 bf16 MFMA
    int m = lane & 15, g = lane >> 4;
    f32x4 acc0 = {0,0,0,0}, acc1 = {0,0,0,0}, acc2 = {0,0,0,0}, acc3 = {0,0,0,0};
    const short* w0 = Wb + (size_t)(wv * 64 + 0  + m) * FD;
    const short* w1 = Wb + (size_t)(wv * 64 + 16 + m) * FD;
    const short* w2 = Wb + (size_t)(wv * 64 + 32 + m) * FD;
    const short* w3 = Wb + (size_t)(wv * 64 + 48 + m) * FD;
#pragma unroll
    for (int ks = 0; ks < 8; ++ks) {
        int ko = ks * 32 + g * 8;
        bf16x8 af = *(const bf16x8*)&Ab[m][ko];
        bf16x8 b0 = *(const bf16x8*)(w0 + ko);
        bf16x8 b1 = *(const bf16x8*)(w1 + ko);
        bf16x8 b2 = *(const bf16x8*)(w2 + ko);
        bf16x8 b3 = *(const bf16x8*)(w3 + ko);
        acc0 = __builtin_amdgcn_mfma_f32_16x16x32_bf16(af, b0, acc0, 0, 0, 0);
        acc1 = __builtin_amdgcn_mfma_f32_16x16x32_bf16(af, b1, acc1, 0, 0, 0);
        acc2 = __builtin_amdgcn_mfma_f32_16x16x32_bf16(af, b2, acc2, 0, 0, 0);
        acc3 = __builtin_amdgcn_mfma_f32_16x16x32_bf16(af, b3, acc3, 0, 0, 0);
    }
#pragma unroll
    for (int nt = 0; nt < 4; ++nt) {
        f32x4 a = nt == 0 ? acc0 : nt == 1 ? acc1 : nt == 2 ? acc2 : acc3;
        int c = wv * 64 + nt * 16 + m;
        float bv = bias[c];
#pragma unroll
        for (int r = 0; r < 4; ++r) {
            out[(size_t)(nbase + g * 4 + r) * FD + c] = a[r] + bv;
        }
    }
}

extern "C" void kernel_launch(void* const* d_in, const int* in_sizes, int n_in,
                              void* d_out, int out_size, void* d_ws, size_t ws_size,
                              hipStream_t stream) {
    const float* x  = (const float*)d_in[0];
    const int*   ei = (const int*)d_in[1];
    const float* cv = (const float*)d_in[2];
    const float* W  = (const float*)d_in[3];
    const float* b  = (const float*)d_in[4];
    float* out = (float*)d_out;

    const int* row = ei;
    const int* col = ei + NE;

    // ws layout (16B-aligned chain)
    ull*      dc     = (ull*)d_ws;                          // NN_PAD * 8B
    unsigned* e_cw   = (unsigned*)(dc + NN_PAD);            // NE * 4B
    unsigned* q8     = e_cw + NE;                           // NN*64 * 4B (12.8MB)
    short*    Wb     = (short*)(q8 + (size_t)NN * 64);      // FD*FD * 2B
    float*    dinv   = (float*)(Wb + (size_t)FD * FD);      // NN_PAD
    float*    scale  = dinv + NN_PAD;                       // NN_PAD
    int*      rs     = (int*)(scale + NN_PAD);              // NN_PAD (uses NN+1)
    int*      cursor = rs + NN_PAD;                         // NN_PAD

    hipMemsetAsync(dc, 0, NN_PAD * sizeof(ull), stream);

    count_deg_kernel<<<(NE + 255) / 256, 256, 0, stream>>>(row, cv, dc);
    scan_all_kernel<<<1, 1024, 0, stream>>>(dc, dinv, rs, cursor);
    quant_kernel<<<NN / 4 + 256, 256, 0, stream>>>(x, W, dinv, q8, scale, Wb);
    bucket_kernel<<<(NE + 255) / 256, 256, 0, stream>>>(row, col, cv, scale, cursor, e_cw);

    fused_kernel<<<NN / NPB, 256, 0, stream>>>(q8, e_cw, rs, dinv, Wb, b, out);
}

// Round 7
// 187.032 us; speedup vs baseline: 1.7108x; 1.7108x over previous
//
#include <hip/hip_runtime.h>
#include <hip/hip_bf16.h>

#define NN 50000
#define NE 800000
#define FD 256
#define NN_PAD 50048       // NN rounded up to multiple of 64
#define SCAN_B 196         // ceil(NN/256)
#define NPB 16             // nodes per block

typedef __attribute__((ext_vector_type(8))) short bf16x8;
typedef __attribute__((ext_vector_type(4))) float f32x4;
typedef unsigned long long ull;

__device__ __forceinline__ short f2bf(float f) {
    union { float f; unsigned u; } v; v.f = f;
    unsigned r = v.u + 0x7fffu + ((v.u >> 16) & 1u);
    return (short)(r >> 16);
}
__device__ __forceinline__ float bf2f(unsigned short u) {
    union { unsigned u; float f; } v; v.u = ((unsigned)u) << 16;
    return v.f;
}

// dc[row] += (1<<40) | fix24(cv)   -- one 64b atomic per edge
__global__ void count_deg_kernel(const int* __restrict__ row, const float* __restrict__ cv,
                                 ull* __restrict__ dc) {
    int e = blockIdx.x * blockDim.x + threadIdx.x;
    if (e < NE) {
        int r = row[e];
        unsigned cf = (unsigned)(cv[e] * 16777216.0f + 0.5f);
        atomicAdd(&dc[r], (1ULL << 40) | (ull)cf);
    }
}

__device__ __forceinline__ int block_excl_scan256(int v, int tid) {
    __shared__ int ws[4];
    int lane = tid & 63, wv = tid >> 6;
    int incl = v;
#pragma unroll
    for (int off = 1; off < 64; off <<= 1) {
        int t = __shfl_up(incl, off);
        if (lane >= off) incl += t;
    }
    if (lane == 63) ws[wv] = incl;
    __syncthreads();
    int acc = 0;
#pragma unroll
    for (int k = 0; k < 4; ++k) if (k < wv) acc += ws[k];
    return acc + incl - v;
}

// per-block count sums -> bsum; dinv = deg^-1/2 (0 if deg==0)
__global__ void sum_dinv_kernel(const ull* __restrict__ dc, float* __restrict__ dinv,
                                int* __restrict__ bsum) {
    int i = blockIdx.x * 256 + threadIdx.x;
    ull v = (i < NN) ? dc[i] : 0ULL;
    int cnt = (int)(v >> 40);
    ull df = v & ((1ULL << 40) - 1);
    int lane = threadIdx.x & 63, wv = threadIdx.x >> 6;
    int s = cnt;
#pragma unroll
    for (int off = 1; off < 64; off <<= 1) s += __shfl_xor(s, off);
    __shared__ int ws[4];
    if (lane == 0) ws[wv] = s;
    __syncthreads();
    if (threadIdx.x == 0) bsum[blockIdx.x] = ws[0] + ws[1] + ws[2] + ws[3];
    if (i < NN) {
        float d = (float)df * (1.0f / 16777216.0f);
        dinv[i] = (df > 0) ? rsqrtf(d) : 0.f;
    }
}

__global__ void scan_bsum_kernel(int* __restrict__ bsum) {
    int tid = threadIdx.x;
    int v = (tid < SCAN_B) ? bsum[tid] : 0;
    int excl = block_excl_scan256(v, tid);
    if (tid < SCAN_B) bsum[tid] = excl;
}

__global__ void write_rs_kernel(const ull* __restrict__ dc, const int* __restrict__ bsum,
                                int* __restrict__ rs, int* __restrict__ cursor) {
    int i = blockIdx.x * 256 + threadIdx.x;
    int v = (i < NN) ? (int)(dc[i] >> 40) : 0;
    int excl = block_excl_scan256(v, threadIdx.x) + bsum[blockIdx.x];
    if (i < NN) { rs[i] = excl; cursor[i] = excl; }
    if (i == NN - 1) rs[NN] = excl + v;
}

// one wave per x-row: xd = x*dinv[r]; s = max|xd|/127; q8 = round(xd*127/max)+128 packed;
// tail blocks convert W -> bf16
__global__ void quant_kernel(const float* __restrict__ x, const float* __restrict__ W,
                             const float* __restrict__ dinv, unsigned* __restrict__ q8,
                             float* __restrict__ scale, short* __restrict__ Wb) {
    int wid = blockIdx.x * 4 + (threadIdx.x >> 6);
    int lane = threadIdx.x & 63;
    if (wid < NN) {
        int r = wid;
        float dr = dinv[r];
        float4 v = *(const float4*)(x + (size_t)r * FD + lane * 4);
        v.x *= dr; v.y *= dr; v.z *= dr; v.w *= dr;
        float m = fmaxf(fmaxf(fabsf(v.x), fabsf(v.y)), fmaxf(fabsf(v.z), fabsf(v.w)));
#pragma unroll
        for (int off = 1; off < 64; off <<= 1) m = fmaxf(m, __shfl_xor(m, off, 64));
        float s   = (m > 0.f) ? m * (1.0f / 127.0f) : 1.0f;
        float inv = (m > 0.f) ? 127.0f / m : 0.f;
        if (lane == 0) scale[r] = s;
        int q0 = (int)rintf(v.x * inv) + 128;
        int q1 = (int)rintf(v.y * inv) + 128;
        int q2 = (int)rintf(v.z * inv) + 128;
        int q3 = (int)rintf(v.w * inv) + 128;
        q8[r * 64 + lane] = (unsigned)q0 | ((unsigned)q1 << 8) |
                            ((unsigned)q2 << 16) | ((unsigned)q3 << 24);
    } else {
        int j = (wid - NN) * 64 + lane;
        if (j < FD * FD) Wb[j] = f2bf(W[j]);
    }
}

// counting-sort edges by destination; pack (w_bf16:16 | col:16), w = cv * scale[col]
__global__ void bucket_kernel(const int* __restrict__ row, const int* __restrict__ col,
                              const float* __restrict__ cv, const float* __restrict__ scale,
                              int* __restrict__ cursor, unsigned* __restrict__ e_cw) {
    int e = blockIdx.x * blockDim.x + threadIdx.x;
    if (e >= NE) return;
    int r = row[e], c = col[e];
    float w = cv[e] * scale[c];
    int idx = atomicAdd(&cursor[r], 1);
    unsigned wb = (unsigned)(unsigned short)f2bf(w);
    e_cw[idx] = (wb << 16) | (unsigned)c;
}

// fused gather (uint8 x, per-row scale folded into edge weight) + bf16 MFMA GEMM.
// Block = 16 nodes, 4 waves; quad (16 lanes) per node, lane = 16 feats (uint4 = 16B).
__global__ __launch_bounds__(256) void fused_kernel(
        const unsigned* __restrict__ q8, const unsigned* __restrict__ e_cw,
        const int* __restrict__ rs, const float* __restrict__ dinv,
        const short* __restrict__ Wb, const float* __restrict__ bias,
        float* __restrict__ out) {
    __shared__ short Ab[NPB][264];
    int tid = threadIdx.x, lane = tid & 63, wv = tid >> 6;
    int q = lane >> 4, i = lane & 15;
    int nbase = blockIdx.x * NPB;
    int n = nbase + wv * 4 + q;

    int e = rs[n], en = rs[n + 1];
    const unsigned* xq = q8 + i * 4;

    float acc[16];
#pragma unroll
    for (int k = 0; k < 16; ++k) acc[k] = 0.f;
    float wsum = 0.f;

#define EDGE(V, CW) do {                                                     \
        float w_ = bf2f((unsigned short)((CW) >> 16));                       \
        wsum += w_;                                                          \
        acc[0]  = fmaf(w_, (float)(unsigned char)((V).x      ), acc[0]);     \
        acc[1]  = fmaf(w_, (float)(unsigned char)((V).x >>  8), acc[1]);     \
        acc[2]  = fmaf(w_, (float)(unsigned char)((V).x >> 16), acc[2]);     \
        acc[3]  = fmaf(w_, (float)((V).x >> 24), acc[3]);                    \
        acc[4]  = fmaf(w_, (float)(unsigned char)((V).y      ), acc[4]);     \
        acc[5]  = fmaf(w_, (float)(unsigned char)((V).y >>  8), acc[5]);     \
        acc[6]  = fmaf(w_, (float)(unsigned char)((V).y >> 16), acc[6]);     \
        acc[7]  = fmaf(w_, (float)((V).y >> 24), acc[7]);                    \
        acc[8]  = fmaf(w_, (float)(unsigned char)((V).z      ), acc[8]);     \
        acc[9]  = fmaf(w_, (float)(unsigned char)((V).z >>  8), acc[9]);     \
        acc[10] = fmaf(w_, (float)(unsigned char)((V).z >> 16), acc[10]);    \
        acc[11] = fmaf(w_, (float)((V).z >> 24), acc[11]);                   \
        acc[12] = fmaf(w_, (float)(unsigned char)((V).w      ), acc[12]);    \
        acc[13] = fmaf(w_, (float)(unsigned char)((V).w >>  8), acc[13]);    \
        acc[14] = fmaf(w_, (float)(unsigned char)((V).w >> 16), acc[14]);    \
        acc[15] = fmaf(w_, (float)((V).w >> 24), acc[15]);                   \
    } while (0)

    // head-peel to 16B alignment of e_cw
    while (e < en && (e & 3)) {
        unsigned cw = e_cw[e];
        uint4 v = *(const uint4*)(xq + (size_t)(cw & 0xFFFFu) * 64);
        EDGE(v, cw);
        ++e;
    }
    // main: 4 edges per iteration, 1 metadata load + 4 x-row loads in flight
    for (; e + 4 <= en; e += 4) {
        uint4 cw4 = *(const uint4*)(e_cw + e);
        uint4 v0 = *(const uint4*)(xq + (size_t)(cw4.x & 0xFFFFu) * 64);
        uint4 v1 = *(const uint4*)(xq + (size_t)(cw4.y & 0xFFFFu) * 64);
        uint4 v2 = *(const uint4*)(xq + (size_t)(cw4.z & 0xFFFFu) * 64);
        uint4 v3 = *(const uint4*)(xq + (size_t)(cw4.w & 0xFFFFu) * 64);
        EDGE(v0, cw4.x);
        EDGE(v1, cw4.y);
        EDGE(v2, cw4.z);
        EDGE(v3, cw4.w);
    }
    for (; e < en; ++e) {
        unsigned cw = e_cw[e];
        uint4 v = *(const uint4*)(xq + (size_t)(cw & 0xFFFFu) * 64);
        EDGE(v, cw);
    }
#undef EDGE

    // remove the +128 bias, apply dinv[row], convert to bf16 in LDS
    {
        float dr = dinv[n];
        float base = 128.f * wsum;
        bf16x8 lo, hi;
#pragma unroll
        for (int k = 0; k < 8; ++k) {
            lo[k] = f2bf((acc[k] - base) * dr);
            hi[k] = f2bf((acc[k + 8] - base) * dr);
        }
        *(bf16x8*)&Ab[wv * 4 + q][i * 16] = lo;
        *(bf16x8*)&Ab[wv * 4 + q][i * 16 + 8] = hi;
    }
    __syncthreads();

    // ---- GEMM: out[nbase..+16][wv*64..+64] via 16x16x32 bf16 MFMA
    int m = lane & 15, g = lane >> 4;
    f32x4 acc0 = {0,0,0,0}, acc1 = {0,0,0,0}, acc2 = {0,0,0,0}, acc3 = {0,0,0,0};
    const short* w0 = Wb + (size_t)(wv * 64 + 0  + m) * FD;
    const short* w1 = Wb + (size_t)(wv * 64 + 16 + m) * FD;
    const short* w2 = Wb + (size_t)(wv * 64 + 32 + m) * FD;
    const short* w3 = Wb + (size_t)(wv * 64 + 48 + m) * FD;
#pragma unroll
    for (int ks = 0; ks < 8; ++ks) {
        int ko = ks * 32 + g * 8;
        bf16x8 af = *(const bf16x8*)&Ab[m][ko];
        bf16x8 b0 = *(const bf16x8*)(w0 + ko);
        bf16x8 b1 = *(const bf16x8*)(w1 + ko);
        bf16x8 b2 = *(const bf16x8*)(w2 + ko);
        bf16x8 b3 = *(const bf16x8*)(w3 + ko);
        acc0 = __builtin_amdgcn_mfma_f32_16x16x32_bf16(af, b0, acc0, 0, 0, 0);
        acc1 = __builtin_amdgcn_mfma_f32_16x16x32_bf16(af, b1, acc1, 0, 0, 0);
        acc2 = __builtin_amdgcn_mfma_f32_16x16x32_bf16(af, b2, acc2, 0, 0, 0);
        acc3 = __builtin_amdgcn_mfma_f32_16x16x32_bf16(af, b3, acc3, 0, 0, 0);
    }
#pragma unroll
    for (int nt = 0; nt < 4; ++nt) {
        f32x4 a = nt == 0 ? acc0 : nt == 1 ? acc1 : nt == 2 ? acc2 : acc3;
        int c = wv * 64 + nt * 16 + m;
        float bv = bias[c];
#pragma unroll
        for (int r = 0; r < 4; ++r) {
            out[(size_t)(nbase + g * 4 + r) * FD + c] = a[r] + bv;
        }
    }
}

extern "C" void kernel_launch(void* const* d_in, const int* in_sizes, int n_in,
                              void* d_out, int out_size, void* d_ws, size_t ws_size,
                              hipStream_t stream) {
    const float* x  = (const float*)d_in[0];
    const int*   ei = (const int*)d_in[1];
    const float* cv = (const float*)d_in[2];
    const float* W  = (const float*)d_in[3];
    const float* b  = (const float*)d_in[4];
    float* out = (float*)d_out;

    const int* row = ei;
    const int* col = ei + NE;

    // ws layout (16B-aligned chain)
    ull*      dc     = (ull*)d_ws;                          // NN_PAD * 8B
    unsigned* e_cw   = (unsigned*)(dc + NN_PAD);            // NE * 4B
    unsigned* q8     = e_cw + NE;                           // NN*64 * 4B (12.8MB)
    short*    Wb     = (short*)(q8 + (size_t)NN * 64);      // FD*FD * 2B
    float*    dinv   = (float*)(Wb + (size_t)FD * FD);      // NN_PAD
    float*    scale  = dinv + NN_PAD;                       // NN_PAD
    int*      rs     = (int*)(scale + NN_PAD);              // NN_PAD (uses NN+1)
    int*      cursor = rs + NN_PAD;                         // NN_PAD
    int*      bsum   = cursor + NN_PAD;                     // 256

    hipMemsetAsync(dc, 0, NN_PAD * sizeof(ull), stream);

    count_deg_kernel<<<(NE + 255) / 256, 256, 0, stream>>>(row, cv, dc);
    sum_dinv_kernel<<<SCAN_B, 256, 0, stream>>>(dc, dinv, bsum);
    scan_bsum_kernel<<<1, 256, 0, stream>>>(bsum);
    write_rs_kernel<<<SCAN_B, 256, 0, stream>>>(dc, bsum, rs, cursor);
    quant_kernel<<<NN / 4 + 256, 256, 0, stream>>>(x, W, dinv, q8, scale, Wb);
    bucket_kernel<<<(NE + 255) / 256, 256, 0, stream>>>(row, col, cv, scale, cursor, e_cw);

    fused_kernel<<<NN / NPB, 256, 0, stream>>>(q8, e_cw, rs, dinv, Wb, b, out);
}